// Round 13
// baseline (202.573 us; speedup 1.0000x reference)
//
#include <hip/hip_runtime.h>
#include <hip/hip_bf16.h>

typedef __bf16 bf16;
typedef __bf16 bf16x8 __attribute__((ext_vector_type(8)));
typedef __bf16 bf16x4v __attribute__((ext_vector_type(4)));
typedef float  f32x4  __attribute__((ext_vector_type(4)));
typedef float  f32x16 __attribute__((ext_vector_type(16)));

#define SEQL  2048
#define BATCH 2
#define HID   2048
#define NH    16
#define NKVH  4
#define HD    128
#define NPROJ 3072
#define MROWS 4096   // SEQL*BATCH

// softmax scale folded into Q at qkv epilogue: scale * log2(e)
#define QSCALE (0.08838834764831845f * 1.44269504088896340f)

__device__ __forceinline__ void gload16(const void* src, void* dst) {
  __builtin_amdgcn_global_load_lds(
      (__attribute__((address_space(1))) void*)src,
      (__attribute__((address_space(3))) void*)dst, 16, 0, 0);
}

// XOR swizzles (involutions; applied identically on staging-source and ds_read)
__device__ __forceinline__ int swz128(int off) { return off ^ (((off >> 7) & 7) << 4); }  // 128B rows
__device__ __forceinline__ int swz256(int off) { return off ^ (((off >> 8) & 7) << 4); }  // 256B rows

__device__ __forceinline__ unsigned cvtpk_bf16(float lo, float hi) {
  unsigned r;
  asm("v_cvt_pk_bf16_f32 %0, %1, %2" : "=v"(r) : "v"(lo), "v"(hi));
  return r;
}
__device__ __forceinline__ void permswap32(unsigned& a, unsigned& b) {
  asm volatile("v_permlane32_swap_b32 %0, %1" : "+v"(a), "+v"(b));
}
__device__ __forceinline__ f32x16 mfma16(bf16x8 a, bf16x8 b, f32x16 c) {
  return __builtin_amdgcn_mfma_f32_32x32x16_bf16(a, b, c, 0, 0, 0);
}
__device__ __forceinline__ float sum16(const f32x16& v) {
  float a = (v[0] + v[1]) + (v[2] + v[3]);
  float b = (v[4] + v[5]) + (v[6] + v[7]);
  float c = (v[8] + v[9]) + (v[10] + v[11]);
  float d = (v[12] + v[13]) + (v[14] + v[15]);
  return (a + b) + (c + d);
}

// ---------------------------------------------------------------- convert (x, w_qkv; w_proj fused into qkv epilogue)
__global__ __launch_bounds__(256) void cvt_kernel(
    const float* __restrict__ x, const float* __restrict__ wq,
    bf16* __restrict__ xo, bf16* __restrict__ wqo) {
  const int NXQ  = (MROWS * HID) / 4;
  const int NWQQ = (NPROJ * HID) / 4;
  const int total = NXQ + NWQQ;
  for (int i = blockIdx.x * blockDim.x + threadIdx.x; i < total; i += gridDim.x * blockDim.x) {
    const float4* src; bf16* dst; int j;
    if (i < NXQ) { src = (const float4*)x;  dst = xo;  j = i; }
    else         { src = (const float4*)wq; dst = wqo; j = i - NXQ; }
    float4 v = src[j];
    bf16x4v o;
    o[0] = (bf16)v.x; o[1] = (bf16)v.y; o[2] = (bf16)v.z; o[3] = (bf16)v.w;
    *(bf16x4v*)(dst + (size_t)j * 4) = o;
  }
}

// ---------------------------------------------------------------- QKV GEMM
// 128x128 tile (longest-validated form, ~905 TF/CU) + w_proj f32->bf16
// conversion fused AFTER the epilogue (r12 win: tail-fusion rides qkv's
// ~2%-busy HBM pipe and overlaps block stragglers; head-fusion in attn
// cost +5us in r7).
__global__ __launch_bounds__(256, 3) void qkv_gemm(
    const bf16* __restrict__ A, const bf16* __restrict__ B,
    bf16* __restrict__ Qo, bf16* __restrict__ Ko, bf16* __restrict__ Vt,
    const float* __restrict__ wp, bf16* __restrict__ wpb) {
  __shared__ char lds[32768];
  const int tid = threadIdx.x, l = tid & 63, w = tid >> 6;
  // XCD-aware swizzle (T1): grid 24x32 = 768 = 8*96
  const int lin = blockIdx.x + 24 * blockIdx.y;
  const int swz = (lin & 7) * 96 + (lin >> 3);
  const int bx = swz % 24, by = swz / 24;
  const int r0 = by * 128, p0 = bx * 128;
  const int wr = w >> 1, wc = w & 1;

  f32x4 acc[4][4];
  const f32x4 fzero = {0.f, 0.f, 0.f, 0.f};
#pragma unroll
  for (int m = 0; m < 4; m++)
#pragma unroll
    for (int n = 0; n < 4; n++) acc[m][n] = fzero;

  for (int kt = 0; kt < HID / 64; ++kt) {
    const int k0 = kt * 64;
    __syncthreads();
#pragma unroll
    for (int q = 0; q < 4; q++) {
      const int doff = (w * 4 + q) * 1024 + l * 16;
      const int row = doff >> 7;
      const int chv = ((doff >> 4) & 7) ^ (row & 7);
      gload16((const char*)A + ((size_t)(r0 + row) * HID + k0) * 2 + chv * 16,
              lds + (w * 4 + q) * 1024);
      gload16((const char*)B + ((size_t)(p0 + row) * HID + k0) * 2 + chv * 16,
              lds + 16384 + (w * 4 + q) * 1024);
    }
    __syncthreads();
    bf16x8 af[4][2], bfr[4][2];
#pragma unroll
    for (int m = 0; m < 4; m++)
#pragma unroll
      for (int kk = 0; kk < 2; kk++) {
        int off = (wr * 64 + m * 16 + (l & 15)) * 128 + kk * 64 + (l >> 4) * 16;
        af[m][kk] = *(const bf16x8*)(lds + swz128(off));
      }
#pragma unroll
    for (int n = 0; n < 4; n++)
#pragma unroll
      for (int kk = 0; kk < 2; kk++) {
        int off = (wc * 64 + n * 16 + (l & 15)) * 128 + kk * 64 + (l >> 4) * 16;
        bfr[n][kk] = *(const bf16x8*)(lds + 16384 + swz128(off));
      }
#pragma unroll
    for (int kk = 0; kk < 2; kk++)
#pragma unroll
      for (int m = 0; m < 4; m++)
#pragma unroll
        for (int n = 0; n < 4; n++)
          acc[m][n] = __builtin_amdgcn_mfma_f32_16x16x32_bf16(af[m][kk], bfr[n][kk], acc[m][n], 0, 0, 0);
  }

  const int seg = (p0 % 768) / 128;
  const int g = p0 / 768;
#pragma unroll
  for (int m = 0; m < 4; m++) {
    const int rbase = r0 + wr * 64 + m * 16 + ((l >> 4) << 2);
#pragma unroll
    for (int n = 0; n < 4; n++) {
      const int c = wc * 64 + n * 16 + (l & 15);  // d within head
#pragma unroll
      for (int rg = 0; rg < 4; ++rg) {
        const int r = rbase + rg;
        const int s = r >> 1, b = r & 1;
        if (seg < 4) {
          const int h = g * 4 + seg;
          // pre-scale Q by softmax-scale*log2e so attn softmax works in exp2 domain
          Qo[(((size_t)(b * 16 + h)) * 2048 + s) * 128 + c] = (bf16)(acc[m][n][rg] * QSCALE);
        } else if (seg == 4) {
          Ko[(((size_t)(b * 4 + g)) * 2048 + s) * 128 + c] = (bf16)acc[m][n][rg];
        } else {
          Vt[(((size_t)(b * 4 + g)) * 128 + c) * 2048 + s] = (bf16)acc[m][n][rg];
        }
      }
    }
  }

  // ---- fused w_proj f32->bf16 conversion (rides qkv's idle HBM pipe) ----
  {
    const int NWPQ = (HID * HID) / 4;                 // 1048576 float4s
    const int nthreads = 768 * 256;                   // grid * block
    for (int i = lin * 256 + tid; i < NWPQ; i += nthreads) {
      float4 v = ((const float4*)wp)[i];
      bf16x4v o;
      o[0] = (bf16)v.x; o[1] = (bf16)v.y; o[2] = (bf16)v.z; o[3] = (bf16)v.w;
      *(bf16x4v*)(wpb + (size_t)i * 4) = o;
    }
  }
}

// ---------------------------------------------------------------- attention
// r12 structure with SETPRIO REMOVED (A/B vs r12's 91.0us): m190 measured
// setprio hurting barrier-locked multi-wave GEMM blocks; m191 measured it
// helping independent 1-wave attn blocks. This kernel is the mixed case
// (2 independent blocks/CU, each 4-wave lockstep) -- resolving the sign.
// Pre-committed read: |delta| <= 1us => neutral, plateau confirmed.
template<int BASE>
__device__ __forceinline__ void attn_tile(
    char* lds, const bf16x8* qf, const int* ka, const int* va,
    f32x16* oacc, float& lp) {
  const f32x16 z16 = {};

  // S^T = mfma(K, Q): lane holds col q=l31; rows t = (reg&3)+8*(reg>>2)+4*h2 (+32*tsub)
  f32x16 sT0 = z16, sT1 = z16;
#pragma unroll
  for (int s = 0; s < 8; s++) {
    bf16x8 kf = *(const bf16x8*)(lds + BASE + ka[s]);
    sT0 = mfma16(kf, qf[s], sT0);
  }
#pragma unroll
  for (int s = 0; s < 8; s++) {
    bf16x8 kf = *(const bf16x8*)(lds + BASE + ka[8 + s]);
    sT1 = mfma16(kf, qf[s], sT1);
  }

  // SM0: P0 = exp2(S0) (static-max; normalized by l at epilogue), pack c0.
  unsigned c0[8], c1[8];
#pragma unroll
  for (int i = 0; i < 16; i++) sT0[i] = exp2f(sT0[i]);
  lp += sum16(sT0);
#pragma unroll
  for (int i = 0; i < 8; i++) c0[i] = cvtpk_bf16(sT0[2 * i], sT0[2 * i + 1]);
  permswap32(c0[0], c0[2]); permswap32(c0[1], c0[3]);
  permswap32(c0[4], c0[6]); permswap32(c0[5], c0[7]);

  // PV ks=0,1 (consumes c0 only) -- issued before SM1's VALU work
#pragma unroll
  for (int ks = 0; ks < 2; ks++) {
    union { unsigned u[4]; bf16x8 v; } pb;
#pragma unroll
    for (int i = 0; i < 4; i++) pb.u[i] = c0[(ks & 1) * 4 + i];
#pragma unroll
    for (int dblk = 0; dblk < 4; dblk++) {
      bf16x8 vf = *(const bf16x8*)(lds + BASE + 16384 + va[ks * 4 + dblk]);
      oacc[dblk] = mfma16(vf, pb.v, oacc[dblk]);
    }
  }

  // SM1 on the VALU while PV ks01 MFMAs drain
#pragma unroll
  for (int i = 0; i < 16; i++) sT1[i] = exp2f(sT1[i]);
  lp += sum16(sT1);
#pragma unroll
  for (int i = 0; i < 8; i++) c1[i] = cvtpk_bf16(sT1[2 * i], sT1[2 * i + 1]);
  permswap32(c1[0], c1[2]); permswap32(c1[1], c1[3]);
  permswap32(c1[4], c1[6]); permswap32(c1[5], c1[7]);

  // PV ks=2,3 (consumes c1)
#pragma unroll
  for (int ks = 2; ks < 4; ks++) {
    union { unsigned u[4]; bf16x8 v; } pb;
#pragma unroll
    for (int i = 0; i < 4; i++) pb.u[i] = c1[(ks & 1) * 4 + i];
#pragma unroll
    for (int dblk = 0; dblk < 4; dblk++) {
      bf16x8 vf = *(const bf16x8*)(lds + BASE + 16384 + va[ks * 4 + dblk]);
      oacc[dblk] = mfma16(vf, pb.v, oacc[dblk]);
    }
  }
}

__global__ __launch_bounds__(256, 2) void attn_kernel(
    const bf16* __restrict__ Q, const bf16* __restrict__ K, const bf16* __restrict__ V,
    bf16* __restrict__ O) {
  __shared__ char lds[65536];  // 2 x { K:[64][128] 16KB, V^T:[128][64] 16KB }
  const int tid = threadIdx.x, l = tid & 63, w = tid >> 6;
  const int l31 = l & 31, h2 = l >> 5;
  // XCD-aware swizzle (T1): 512 blocks = 8*64
  const int lin = blockIdx.x + (blockIdx.y << 4);
  const int swzb = (lin & 7) * 64 + (lin >> 3);
  const int qt = swzb & 15, bh = swzb >> 4;
  const int b = bh >> 4, head = bh & 15, g = head >> 2;

  const int q0 = qt * 128 + w * 32;

  // Q as MFMA B-operand: lane holds col q = l31, k-elems d = 16s + 8*h2 + j
  bf16x8 qf[8];
  {
    const bf16* qbase = Q + (((size_t)(b * 16 + head)) * 2048 + q0 + l31) * 128 + h2 * 8;
#pragma unroll
    for (int s = 0; s < 8; s++) qf[s] = *(const bf16x8*)(qbase + s * 16);
  }

  // hoisted per-lane ds_read offsets (loop-invariant)
  int ka[16], va[16];
#pragma unroll
  for (int tsub = 0; tsub < 2; tsub++)
#pragma unroll
    for (int s = 0; s < 8; s++)
      ka[tsub * 8 + s] = swz256((tsub * 32 + l31) * 256 + s * 32 + h2 * 16);
#pragma unroll
  for (int ks = 0; ks < 4; ks++)
#pragma unroll
    for (int dblk = 0; dblk < 4; dblk++)
      va[ks * 4 + dblk] = swz128((dblk * 32 + l31) * 128 + ks * 32 + h2 * 16);

  // hoisted staging source offsets
  int kso[4], vso[4];
#pragma unroll
  for (int q = 0; q < 4; q++) {
    const int off = (q * 4 + w) * 1024 + l * 16;
    kso[q] = swz256(off);
    const int rowv = off >> 7;
    const int chv = ((off >> 4) & 7) ^ (rowv & 7);
    vso[q] = rowv * 4096 + chv * 16;  // bytes: (rowv*2048)*2 + chv*16
  }

  const f32x16 z16 = {};
  f32x16 oacc[4];
#pragma unroll
  for (int d = 0; d < 4; d++) oacc[d] = z16;
  float lp = 0.f;

  const char* kbase = (const char*)(K + ((size_t)(b * 4 + g)) * 2048 * 128);
  const char* vbase = (const char*)(V + ((size_t)(b * 4 + g)) * 128 * 2048);

  // stage(tile t, buffer base B)
  auto stage = [&](int t0, int B) {
#pragma unroll
    for (int q = 0; q < 4; q++) {
      gload16(kbase + (size_t)t0 * 256 + kso[q], lds + B + (q * 4 + w) * 1024);
      gload16(vbase + (size_t)t0 * 2 + vso[q], lds + B + 16384 + (q * 4 + w) * 1024);
    }
  };

  stage(0, 0);
  __syncthreads();

  for (int t0 = 0; t0 < SEQL; t0 += 128) {
    stage(t0 + 64, 32768);
    attn_tile<0>(lds, qf, ka, va, oacc, lp);
    __syncthreads();
    if (t0 + 128 < SEQL) stage(t0 + 128, 0);
    attn_tile<32768>(lds, qf, ka, va, oacc, lp);
    __syncthreads();
  }

  // epilogue: lane owns q = q0+l31; O^T reg r of oacc[dblk] is d = 32*dblk + 8*(r>>2) + 4*h2 + (r&3)
  // l(q) = lp(h2) + lp(h2^1): the two h2 halves partition the kv rows.
  const float inv = 1.0f / (lp + __shfl_xor(lp, 32));
  const size_t rowo = ((size_t)(q0 + l31) * 2 + b) * 2048 + (size_t)head * 128;
#pragma unroll
  for (int dblk = 0; dblk < 4; dblk++)
#pragma unroll
    for (int g4 = 0; g4 < 4; g4++) {
      bf16x4v ov;
#pragma unroll
      for (int e = 0; e < 4; e++) ov[e] = (bf16)(oacc[dblk][g4 * 4 + e] * inv);
      *(bf16x4v*)(O + rowo + dblk * 32 + g4 * 8 + h2 * 4) = ov;
    }
}

// ---------------------------------------------------------------- proj GEMM
// 128x128 tile (validated form, ~905 TF/CU).
__global__ __launch_bounds__(256, 2) void proj_gemm(
    const bf16* __restrict__ A, const bf16* __restrict__ B, float* __restrict__ C) {
  __shared__ char lds[32768];
  const int tid = threadIdx.x, l = tid & 63, w = tid >> 6;
  // XCD-aware swizzle (T1): 512 blocks = 8*64
  const int lin = blockIdx.x + (blockIdx.y << 4);
  const int swz = (lin & 7) * 64 + (lin >> 3);
  const int bx = swz & 15, by = swz >> 4;
  const int r0 = by * 128, p0 = bx * 128;
  const int wr = w >> 1, wc = w & 1;

  f32x4 acc[4][4];
  const f32x4 fzero = {0.f, 0.f, 0.f, 0.f};
#pragma unroll
  for (int m = 0; m < 4; m++)
#pragma unroll
    for (int n = 0; n < 4; n++) acc[m][n] = fzero;

  for (int kt = 0; kt < HID / 64; ++kt) {
    const int k0 = kt * 64;
    __syncthreads();
#pragma unroll
    for (int q = 0; q < 4; q++) {
      const int doff = (w * 4 + q) * 1024 + l * 16;
      const int row = doff >> 7;
      const int chv = ((doff >> 4) & 7) ^ (row & 7);
      gload16((const char*)A + ((size_t)(r0 + row) * HID + k0) * 2 + chv * 16,
              lds + (w * 4 + q) * 1024);
      gload16((const char*)B + ((size_t)(p0 + row) * HID + k0) * 2 + chv * 16,
              lds + 16384 + (w * 4 + q) * 1024);
    }
    __syncthreads();
    bf16x8 af[4][2], bfr[4][2];
#pragma unroll
    for (int m = 0; m < 4; m++)
#pragma unroll
      for (int kk = 0; kk < 2; kk++) {
        int off = (wr * 64 + m * 16 + (l & 15)) * 128 + kk * 64 + (l >> 4) * 16;
        af[m][kk] = *(const bf16x8*)(lds + swz128(off));
      }
#pragma unroll
    for (int n = 0; n < 4; n++)
#pragma unroll
      for (int kk = 0; kk < 2; kk++) {
        int off = (wc * 64 + n * 16 + (l & 15)) * 128 + kk * 64 + (l >> 4) * 16;
        bfr[n][kk] = *(const bf16x8*)(lds + 16384 + swz128(off));
      }
#pragma unroll
    for (int kk = 0; kk < 2; kk++)
#pragma unroll
      for (int m = 0; m < 4; m++)
#pragma unroll
        for (int n = 0; n < 4; n++)
          acc[m][n] = __builtin_amdgcn_mfma_f32_16x16x32_bf16(af[m][kk], bfr[n][kk], acc[m][n], 0, 0, 0);
  }
#pragma unroll
  for (int m = 0; m < 4; m++) {
    const int rbase = r0 + wr * 64 + m * 16 + ((l >> 4) << 2);
#pragma unroll
    for (int n = 0; n < 4; n++) {
      const int c = p0 + wc * 64 + n * 16 + (l & 15);
#pragma unroll
      for (int rg = 0; rg < 4; ++rg)
        C[(size_t)(rbase + rg) * HID + c] = acc[m][n][rg];
    }
  }
}

// ---------------------------------------------------------------- launch
extern "C" void kernel_launch(void* const* d_in, const int* in_sizes, int n_in,
                              void* d_out, int out_size, void* d_ws, size_t ws_size,
                              hipStream_t stream) {
  const float* x  = (const float*)d_in[0];
  const float* wq = (const float*)d_in[1];
  const float* wp = (const float*)d_in[2];
  float* out = (float*)d_out;
  char* ws = (char*)d_ws;

  size_t off = 0;
  bf16* xb  = (bf16*)(ws + off); off += (size_t)MROWS * HID * 2;   // 16 MB (reused as O later)
  bf16* wqb = (bf16*)(ws + off); off += (size_t)NPROJ * HID * 2;   // 12 MB
  bf16* wpb = (bf16*)(ws + off); off += (size_t)HID * HID * 2;     //  8 MB
  bf16* Qb  = (bf16*)(ws + off); off += (size_t)2 * 16 * 2048 * 128 * 2;  // 16 MB
  bf16* Kb  = (bf16*)(ws + off); off += (size_t)2 * 4 * 2048 * 128 * 2;   //  4 MB
  bf16* Vb  = (bf16*)(ws + off); off += (size_t)2 * 4 * 128 * 2048 * 2;   //  4 MB
  bf16* Ob  = xb;  // x_bf16 is dead after qkv_gemm; alias O onto it

  cvt_kernel<<<2048, 256, 0, stream>>>(x, wq, xb, wqb);
  qkv_gemm<<<dim3(24, 32), 256, 0, stream>>>(xb, wqb, Qb, Kb, Vb, wp, wpb);
  attn_kernel<<<dim3(16, 32), 256, 0, stream>>>(Qb, Kb, Vb, Ob);
  proj_gemm<<<dim3(16, 32), 256, 0, stream>>>(Ob, wpb, out);
}

// Round 14
// 201.369 us; speedup vs baseline: 1.0060x; 1.0060x over previous
//
#include <hip/hip_runtime.h>
#include <hip/hip_bf16.h>

typedef __bf16 bf16;
typedef __bf16 bf16x8 __attribute__((ext_vector_type(8)));
typedef __bf16 bf16x4v __attribute__((ext_vector_type(4)));
typedef float  f32x4  __attribute__((ext_vector_type(4)));
typedef float  f32x16 __attribute__((ext_vector_type(16)));

#define SEQL  2048
#define BATCH 2
#define HID   2048
#define NH    16
#define NKVH  4
#define HD    128
#define NPROJ 3072
#define MROWS 4096   // SEQL*BATCH

// softmax scale folded into Q at qkv epilogue: scale * log2(e)
#define QSCALE (0.08838834764831845f * 1.44269504088896340f)

__device__ __forceinline__ void gload16(const void* src, void* dst) {
  __builtin_amdgcn_global_load_lds(
      (__attribute__((address_space(1))) void*)src,
      (__attribute__((address_space(3))) void*)dst, 16, 0, 0);
}

// XOR swizzles (involutions; applied identically on staging-source and ds_read)
__device__ __forceinline__ int swz128(int off) { return off ^ (((off >> 7) & 7) << 4); }  // 128B rows
__device__ __forceinline__ int swz256(int off) { return off ^ (((off >> 8) & 7) << 4); }  // 256B rows

__device__ __forceinline__ unsigned cvtpk_bf16(float lo, float hi) {
  unsigned r;
  asm("v_cvt_pk_bf16_f32 %0, %1, %2" : "=v"(r) : "v"(lo), "v"(hi));
  return r;
}
__device__ __forceinline__ void permswap32(unsigned& a, unsigned& b) {
  asm volatile("v_permlane32_swap_b32 %0, %1" : "+v"(a), "+v"(b));
}
__device__ __forceinline__ f32x16 mfma16(bf16x8 a, bf16x8 b, f32x16 c) {
  return __builtin_amdgcn_mfma_f32_32x32x16_bf16(a, b, c, 0, 0, 0);
}
__device__ __forceinline__ float sum16(const f32x16& v) {
  float a = (v[0] + v[1]) + (v[2] + v[3]);
  float b = (v[4] + v[5]) + (v[6] + v[7]);
  float c = (v[8] + v[9]) + (v[10] + v[11]);
  float d = (v[12] + v[13]) + (v[14] + v[15]);
  return (a + b) + (c + d);
}

// ---------------------------------------------------------------- convert (x, w_qkv; w_proj fused into qkv epilogue)
__global__ __launch_bounds__(256) void cvt_kernel(
    const float* __restrict__ x, const float* __restrict__ wq,
    bf16* __restrict__ xo, bf16* __restrict__ wqo) {
  const int NXQ  = (MROWS * HID) / 4;
  const int NWQQ = (NPROJ * HID) / 4;
  const int total = NXQ + NWQQ;
  for (int i = blockIdx.x * blockDim.x + threadIdx.x; i < total; i += gridDim.x * blockDim.x) {
    const float4* src; bf16* dst; int j;
    if (i < NXQ) { src = (const float4*)x;  dst = xo;  j = i; }
    else         { src = (const float4*)wq; dst = wqo; j = i - NXQ; }
    float4 v = src[j];
    bf16x4v o;
    o[0] = (bf16)v.x; o[1] = (bf16)v.y; o[2] = (bf16)v.z; o[3] = (bf16)v.w;
    *(bf16x4v*)(dst + (size_t)j * 4) = o;
  }
}

// ---------------------------------------------------------------- QKV GEMM
// 128x128 tile (longest-validated form, ~905 TF/CU) + w_proj f32->bf16
// conversion fused AFTER the epilogue (r12 win: tail-fusion rides qkv's
// ~2%-busy HBM pipe and overlaps block stragglers; head-fusion in attn
// cost +5us in r7).
__global__ __launch_bounds__(256, 3) void qkv_gemm(
    const bf16* __restrict__ A, const bf16* __restrict__ B,
    bf16* __restrict__ Qo, bf16* __restrict__ Ko, bf16* __restrict__ Vt,
    const float* __restrict__ wp, bf16* __restrict__ wpb) {
  __shared__ char lds[32768];
  const int tid = threadIdx.x, l = tid & 63, w = tid >> 6;
  // XCD-aware swizzle (T1): grid 24x32 = 768 = 8*96
  const int lin = blockIdx.x + 24 * blockIdx.y;
  const int swz = (lin & 7) * 96 + (lin >> 3);
  const int bx = swz % 24, by = swz / 24;
  const int r0 = by * 128, p0 = bx * 128;
  const int wr = w >> 1, wc = w & 1;

  f32x4 acc[4][4];
  const f32x4 fzero = {0.f, 0.f, 0.f, 0.f};
#pragma unroll
  for (int m = 0; m < 4; m++)
#pragma unroll
    for (int n = 0; n < 4; n++) acc[m][n] = fzero;

  for (int kt = 0; kt < HID / 64; ++kt) {
    const int k0 = kt * 64;
    __syncthreads();
#pragma unroll
    for (int q = 0; q < 4; q++) {
      const int doff = (w * 4 + q) * 1024 + l * 16;
      const int row = doff >> 7;
      const int chv = ((doff >> 4) & 7) ^ (row & 7);
      gload16((const char*)A + ((size_t)(r0 + row) * HID + k0) * 2 + chv * 16,
              lds + (w * 4 + q) * 1024);
      gload16((const char*)B + ((size_t)(p0 + row) * HID + k0) * 2 + chv * 16,
              lds + 16384 + (w * 4 + q) * 1024);
    }
    __syncthreads();
    bf16x8 af[4][2], bfr[4][2];
#pragma unroll
    for (int m = 0; m < 4; m++)
#pragma unroll
      for (int kk = 0; kk < 2; kk++) {
        int off = (wr * 64 + m * 16 + (l & 15)) * 128 + kk * 64 + (l >> 4) * 16;
        af[m][kk] = *(const bf16x8*)(lds + swz128(off));
      }
#pragma unroll
    for (int n = 0; n < 4; n++)
#pragma unroll
      for (int kk = 0; kk < 2; kk++) {
        int off = (wc * 64 + n * 16 + (l & 15)) * 128 + kk * 64 + (l >> 4) * 16;
        bfr[n][kk] = *(const bf16x8*)(lds + 16384 + swz128(off));
      }
#pragma unroll
    for (int kk = 0; kk < 2; kk++)
#pragma unroll
      for (int m = 0; m < 4; m++)
#pragma unroll
        for (int n = 0; n < 4; n++)
          acc[m][n] = __builtin_amdgcn_mfma_f32_16x16x32_bf16(af[m][kk], bfr[n][kk], acc[m][n], 0, 0, 0);
  }

  const int seg = (p0 % 768) / 128;
  const int g = p0 / 768;
#pragma unroll
  for (int m = 0; m < 4; m++) {
    const int rbase = r0 + wr * 64 + m * 16 + ((l >> 4) << 2);
#pragma unroll
    for (int n = 0; n < 4; n++) {
      const int c = wc * 64 + n * 16 + (l & 15);  // d within head
#pragma unroll
      for (int rg = 0; rg < 4; ++rg) {
        const int r = rbase + rg;
        const int s = r >> 1, b = r & 1;
        if (seg < 4) {
          const int h = g * 4 + seg;
          // pre-scale Q by softmax-scale*log2e so attn softmax works in exp2 domain
          Qo[(((size_t)(b * 16 + h)) * 2048 + s) * 128 + c] = (bf16)(acc[m][n][rg] * QSCALE);
        } else if (seg == 4) {
          Ko[(((size_t)(b * 4 + g)) * 2048 + s) * 128 + c] = (bf16)acc[m][n][rg];
        } else {
          Vt[(((size_t)(b * 4 + g)) * 128 + c) * 2048 + s] = (bf16)acc[m][n][rg];
        }
      }
    }
  }

  // ---- fused w_proj f32->bf16 conversion (rides qkv's idle HBM pipe) ----
  {
    const int NWPQ = (HID * HID) / 4;                 // 1048576 float4s
    const int nthreads = 768 * 256;                   // grid * block
    for (int i = lin * 256 + tid; i < NWPQ; i += nthreads) {
      float4 v = ((const float4*)wp)[i];
      bf16x4v o;
      o[0] = (bf16)v.x; o[1] = (bf16)v.y; o[2] = (bf16)v.z; o[3] = (bf16)v.w;
      *(bf16x4v*)(wpb + (size_t)i * 4) = o;
    }
  }
}

// ---------------------------------------------------------------- attention
// Best-measured structure (r12, 91.0us): q=32/wave, 512 blocks, 2 blocks/CU,
// K+V LDS dbuf, static-max softmax (P = exp2(S), normalize by l at
// epilogue), SM/PV interleave, VALU l-sum, setprio around MFMA clusters
// (r13 A/B: removing setprio cost +1.9us -> kept).
template<int BASE>
__device__ __forceinline__ void attn_tile(
    char* lds, const bf16x8* qf, const int* ka, const int* va,
    f32x16* oacc, float& lp) {
  const f32x16 z16 = {};

  // S^T = mfma(K, Q): lane holds col q=l31; rows t = (reg&3)+8*(reg>>2)+4*h2 (+32*tsub)
  f32x16 sT0 = z16, sT1 = z16;
  __builtin_amdgcn_s_setprio(1);
#pragma unroll
  for (int s = 0; s < 8; s++) {
    bf16x8 kf = *(const bf16x8*)(lds + BASE + ka[s]);
    sT0 = mfma16(kf, qf[s], sT0);
  }
#pragma unroll
  for (int s = 0; s < 8; s++) {
    bf16x8 kf = *(const bf16x8*)(lds + BASE + ka[8 + s]);
    sT1 = mfma16(kf, qf[s], sT1);
  }
  __builtin_amdgcn_s_setprio(0);

  // SM0: P0 = exp2(S0) (static-max; normalized by l at epilogue), pack c0.
  unsigned c0[8], c1[8];
#pragma unroll
  for (int i = 0; i < 16; i++) sT0[i] = exp2f(sT0[i]);
  lp += sum16(sT0);
#pragma unroll
  for (int i = 0; i < 8; i++) c0[i] = cvtpk_bf16(sT0[2 * i], sT0[2 * i + 1]);
  permswap32(c0[0], c0[2]); permswap32(c0[1], c0[3]);
  permswap32(c0[4], c0[6]); permswap32(c0[5], c0[7]);

  // PV ks=0,1 (consumes c0 only) -- issued before SM1's VALU work
  __builtin_amdgcn_s_setprio(1);
#pragma unroll
  for (int ks = 0; ks < 2; ks++) {
    union { unsigned u[4]; bf16x8 v; } pb;
#pragma unroll
    for (int i = 0; i < 4; i++) pb.u[i] = c0[(ks & 1) * 4 + i];
#pragma unroll
    for (int dblk = 0; dblk < 4; dblk++) {
      bf16x8 vf = *(const bf16x8*)(lds + BASE + 16384 + va[ks * 4 + dblk]);
      oacc[dblk] = mfma16(vf, pb.v, oacc[dblk]);
    }
  }
  __builtin_amdgcn_s_setprio(0);

  // SM1 on the VALU while PV ks01 MFMAs drain
#pragma unroll
  for (int i = 0; i < 16; i++) sT1[i] = exp2f(sT1[i]);
  lp += sum16(sT1);
#pragma unroll
  for (int i = 0; i < 8; i++) c1[i] = cvtpk_bf16(sT1[2 * i], sT1[2 * i + 1]);
  permswap32(c1[0], c1[2]); permswap32(c1[1], c1[3]);
  permswap32(c1[4], c1[6]); permswap32(c1[5], c1[7]);

  // PV ks=2,3 (consumes c1)
  __builtin_amdgcn_s_setprio(1);
#pragma unroll
  for (int ks = 2; ks < 4; ks++) {
    union { unsigned u[4]; bf16x8 v; } pb;
#pragma unroll
    for (int i = 0; i < 4; i++) pb.u[i] = c1[(ks & 1) * 4 + i];
#pragma unroll
    for (int dblk = 0; dblk < 4; dblk++) {
      bf16x8 vf = *(const bf16x8*)(lds + BASE + 16384 + va[ks * 4 + dblk]);
      oacc[dblk] = mfma16(vf, pb.v, oacc[dblk]);
    }
  }
  __builtin_amdgcn_s_setprio(0);
}

__global__ __launch_bounds__(256, 2) void attn_kernel(
    const bf16* __restrict__ Q, const bf16* __restrict__ K, const bf16* __restrict__ V,
    bf16* __restrict__ O) {
  __shared__ char lds[65536];  // 2 x { K:[64][128] 16KB, V^T:[128][64] 16KB }
  const int tid = threadIdx.x, l = tid & 63, w = tid >> 6;
  const int l31 = l & 31, h2 = l >> 5;
  // XCD-aware swizzle (T1): 512 blocks = 8*64
  const int lin = blockIdx.x + (blockIdx.y << 4);
  const int swzb = (lin & 7) * 64 + (lin >> 3);
  const int qt = swzb & 15, bh = swzb >> 4;
  const int b = bh >> 4, head = bh & 15, g = head >> 2;

  const int q0 = qt * 128 + w * 32;

  // Q as MFMA B-operand: lane holds col q = l31, k-elems d = 16s + 8*h2 + j
  bf16x8 qf[8];
  {
    const bf16* qbase = Q + (((size_t)(b * 16 + head)) * 2048 + q0 + l31) * 128 + h2 * 8;
#pragma unroll
    for (int s = 0; s < 8; s++) qf[s] = *(const bf16x8*)(qbase + s * 16);
  }

  // hoisted per-lane ds_read offsets (loop-invariant)
  int ka[16], va[16];
#pragma unroll
  for (int tsub = 0; tsub < 2; tsub++)
#pragma unroll
    for (int s = 0; s < 8; s++)
      ka[tsub * 8 + s] = swz256((tsub * 32 + l31) * 256 + s * 32 + h2 * 16);
#pragma unroll
  for (int ks = 0; ks < 4; ks++)
#pragma unroll
    for (int dblk = 0; dblk < 4; dblk++)
      va[ks * 4 + dblk] = swz128((dblk * 32 + l31) * 128 + ks * 32 + h2 * 16);

  // hoisted staging source offsets
  int kso[4], vso[4];
#pragma unroll
  for (int q = 0; q < 4; q++) {
    const int off = (q * 4 + w) * 1024 + l * 16;
    kso[q] = swz256(off);
    const int rowv = off >> 7;
    const int chv = ((off >> 4) & 7) ^ (rowv & 7);
    vso[q] = rowv * 4096 + chv * 16;  // bytes: (rowv*2048)*2 + chv*16
  }

  const f32x16 z16 = {};
  f32x16 oacc[4];
#pragma unroll
  for (int d = 0; d < 4; d++) oacc[d] = z16;
  float lp = 0.f;

  const char* kbase = (const char*)(K + ((size_t)(b * 4 + g)) * 2048 * 128);
  const char* vbase = (const char*)(V + ((size_t)(b * 4 + g)) * 128 * 2048);

  // stage(tile t, buffer base B)
  auto stage = [&](int t0, int B) {
#pragma unroll
    for (int q = 0; q < 4; q++) {
      gload16(kbase + (size_t)t0 * 256 + kso[q], lds + B + (q * 4 + w) * 1024);
      gload16(vbase + (size_t)t0 * 2 + vso[q], lds + B + 16384 + (q * 4 + w) * 1024);
    }
  };

  stage(0, 0);
  __syncthreads();

  for (int t0 = 0; t0 < SEQL; t0 += 128) {
    stage(t0 + 64, 32768);
    attn_tile<0>(lds, qf, ka, va, oacc, lp);
    __syncthreads();
    if (t0 + 128 < SEQL) stage(t0 + 128, 0);
    attn_tile<32768>(lds, qf, ka, va, oacc, lp);
    __syncthreads();
  }

  // epilogue: lane owns q = q0+l31; O^T reg r of oacc[dblk] is d = 32*dblk + 8*(r>>2) + 4*h2 + (r&3)
  // l(q) = lp(h2) + lp(h2^1): the two h2 halves partition the kv rows.
  const float inv = 1.0f / (lp + __shfl_xor(lp, 32));
  const size_t rowo = ((size_t)(q0 + l31) * 2 + b) * 2048 + (size_t)head * 128;
#pragma unroll
  for (int dblk = 0; dblk < 4; dblk++)
#pragma unroll
    for (int g4 = 0; g4 < 4; g4++) {
      bf16x4v ov;
#pragma unroll
      for (int e = 0; e < 4; e++) ov[e] = (bf16)(oacc[dblk][g4 * 4 + e] * inv);
      *(bf16x4v*)(O + rowo + dblk * 32 + g4 * 8 + h2 * 4) = ov;
    }
}

// ---------------------------------------------------------------- proj GEMM
// 128x128 tile (validated form, ~905 TF/CU).
__global__ __launch_bounds__(256, 2) void proj_gemm(
    const bf16* __restrict__ A, const bf16* __restrict__ B, float* __restrict__ C) {
  __shared__ char lds[32768];
  const int tid = threadIdx.x, l = tid & 63, w = tid >> 6;
  // XCD-aware swizzle (T1): 512 blocks = 8*64
  const int lin = blockIdx.x + (blockIdx.y << 4);
  const int swz = (lin & 7) * 64 + (lin >> 3);
  const int bx = swz & 15, by = swz >> 4;
  const int r0 = by * 128, p0 = bx * 128;
  const int wr = w >> 1, wc = w & 1;

  f32x4 acc[4][4];
  const f32x4 fzero = {0.f, 0.f, 0.f, 0.f};
#pragma unroll
  for (int m = 0; m < 4; m++)
#pragma unroll
    for (int n = 0; n < 4; n++) acc[m][n] = fzero;

  for (int kt = 0; kt < HID / 64; ++kt) {
    const int k0 = kt * 64;
    __syncthreads();
#pragma unroll
    for (int q = 0; q < 4; q++) {
      const int doff = (w * 4 + q) * 1024 + l * 16;
      const int row = doff >> 7;
      const int chv = ((doff >> 4) & 7) ^ (row & 7);
      gload16((const char*)A + ((size_t)(r0 + row) * HID + k0) * 2 + chv * 16,
              lds + (w * 4 + q) * 1024);
      gload16((const char*)B + ((size_t)(p0 + row) * HID + k0) * 2 + chv * 16,
              lds + 16384 + (w * 4 + q) * 1024);
    }
    __syncthreads();
    bf16x8 af[4][2], bfr[4][2];
#pragma unroll
    for (int m = 0; m < 4; m++)
#pragma unroll
      for (int kk = 0; kk < 2; kk++) {
        int off = (wr * 64 + m * 16 + (l & 15)) * 128 + kk * 64 + (l >> 4) * 16;
        af[m][kk] = *(const bf16x8*)(lds + swz128(off));
      }
#pragma unroll
    for (int n = 0; n < 4; n++)
#pragma unroll
      for (int kk = 0; kk < 2; kk++) {
        int off = (wc * 64 + n * 16 + (l & 15)) * 128 + kk * 64 + (l >> 4) * 16;
        bfr[n][kk] = *(const bf16x8*)(lds + 16384 + swz128(off));
      }
#pragma unroll
    for (int kk = 0; kk < 2; kk++)
#pragma unroll
      for (int m = 0; m < 4; m++)
#pragma unroll
        for (int n = 0; n < 4; n++)
          acc[m][n] = __builtin_amdgcn_mfma_f32_16x16x32_bf16(af[m][kk], bfr[n][kk], acc[m][n], 0, 0, 0);
  }
#pragma unroll
  for (int m = 0; m < 4; m++) {
    const int rbase = r0 + wr * 64 + m * 16 + ((l >> 4) << 2);
#pragma unroll
    for (int n = 0; n < 4; n++) {
      const int c = p0 + wc * 64 + n * 16 + (l & 15);
#pragma unroll
      for (int rg = 0; rg < 4; ++rg)
        C[(size_t)(rbase + rg) * HID + c] = acc[m][n][rg];
    }
  }
}

// ---------------------------------------------------------------- launch
extern "C" void kernel_launch(void* const* d_in, const int* in_sizes, int n_in,
                              void* d_out, int out_size, void* d_ws, size_t ws_size,
                              hipStream_t stream) {
  const float* x  = (const float*)d_in[0];
  const float* wq = (const float*)d_in[1];
  const float* wp = (const float*)d_in[2];
  float* out = (float*)d_out;
  char* ws = (char*)d_ws;

  size_t off = 0;
  bf16* xb  = (bf16*)(ws + off); off += (size_t)MROWS * HID * 2;   // 16 MB (reused as O later)
  bf16* wqb = (bf16*)(ws + off); off += (size_t)NPROJ * HID * 2;   // 12 MB
  bf16* wpb = (bf16*)(ws + off); off += (size_t)HID * HID * 2;     //  8 MB
  bf16* Qb  = (bf16*)(ws + off); off += (size_t)2 * 16 * 2048 * 128 * 2;  // 16 MB
  bf16* Kb  = (bf16*)(ws + off); off += (size_t)2 * 4 * 2048 * 128 * 2;   //  4 MB
  bf16* Vb  = (bf16*)(ws + off); off += (size_t)2 * 4 * 128 * 2048 * 2;   //  4 MB
  bf16* Ob  = xb;  // x_bf16 is dead after qkv_gemm; alias O onto it

  cvt_kernel<<<2048, 256, 0, stream>>>(x, wq, xb, wqb);
  qkv_gemm<<<dim3(24, 32), 256, 0, stream>>>(xb, wqb, Qb, Kb, Vb, wp, wpb);
  attn_kernel<<<dim3(16, 32), 256, 0, stream>>>(Qb, Kb, Vb, Ob);
  proj_gemm<<<dim3(16, 32), 256, 0, stream>>>(Ob, wpb, out);
}